// Round 8
// baseline (303.947 us; speedup 1.0000x reference)
//
#include <hip/hip_runtime.h>
#include <hip/hip_bf16.h>
#include <stdint.h>

// GatedScreeningTile: B=2 N=2048 DIM=2048 H=16 DK=64 DV=128 DIM_INNER=3072
// Pipeline: cvt/transpose -> 256^2 8-phase GEMM(qg|kv) -> normalize -> fused attn -> GEMM(out)

typedef unsigned short u16;
typedef __bf16 bf16x8 __attribute__((ext_vector_type(8)));
typedef u16 u16x8 __attribute__((ext_vector_type(8)));
typedef float f32x4 __attribute__((ext_vector_type(4)));
typedef float f32x16 __attribute__((ext_vector_type(16)));
typedef int i32x4 __attribute__((ext_vector_type(4)));

#define DEVINL __device__ __forceinline__

DEVINL u16 f2bf(float f) {
  union { float f; uint32_t u; } v; v.f = f;
  uint32_t r = (v.u + 0x7FFFu + ((v.u >> 16) & 1u)) >> 16;
  return (u16)r;
}
DEVINL float bf2f(u16 x) {
  union { uint32_t u; float f; } v; v.u = ((uint32_t)x) << 16;
  return v.f;
}
DEVINL bf16x8 as_bf(u16x8 v) { return __builtin_bit_cast(bf16x8, v); }

typedef const __attribute__((address_space(1))) uint32_t* gptr_t;
typedef __attribute__((address_space(3))) uint32_t* lptr_t;
DEVINL void gload_lds16(const void* g, void* l) {
  __builtin_amdgcn_global_load_lds((gptr_t)g, (lptr_t)l, 16, 0, 0);
}

DEVINL f32x4 mfma16(u16x8 a, u16x8 b, f32x4 c) {
  return __builtin_amdgcn_mfma_f32_16x16x32_bf16(as_bf(a), as_bf(b), c, 0, 0, 0);
}
DEVINL f32x16 mfma32(u16x8 a, u16x8 b, f32x16 c) {
  return __builtin_amdgcn_mfma_f32_32x32x16_bf16(as_bf(a), as_bf(b), c, 0, 0, 0);
}

// ---------------- fp32 -> bf16 convert (same layout) ----------------
__global__ void k_cvt(const float* __restrict__ src, u16* __restrict__ dst, int n) {
  int i = (blockIdx.x * blockDim.x + threadIdx.x) * 4;
  int stride = gridDim.x * blockDim.x * 4;
  for (; i < n; i += stride) {
    float4 f = *(const float4*)(src + i);
    ushort4 o;
    o.x = f2bf(f.x); o.y = f2bf(f.y); o.z = f2bf(f.z); o.w = f2bf(f.w);
    *(ushort4*)(dst + i) = o;
  }
}

// ---------------- fp32 (RxC) -> bf16 transposed (CxR) ----------------
__global__ void k_cvtT(const float* __restrict__ src, u16* __restrict__ dst, int R, int C) {
  __shared__ float tile[32][33];
  int c0 = blockIdx.x * 32, r0 = blockIdx.y * 32;
  int tc = threadIdx.x & 31, tr = threadIdx.x >> 5;  // tr 0..7
#pragma unroll
  for (int i = 0; i < 4; i++) {
    int r = tr + i * 8;
    tile[r][tc] = src[(size_t)(r0 + r) * C + c0 + tc];
  }
  __syncthreads();
#pragma unroll
  for (int i = 0; i < 4; i++) {
    int r = tr + i * 8;  // row in dst tile (= src col)
    dst[(size_t)(c0 + r) * R + r0 + tc] = f2bf(tile[tc][r]);
  }
}

// ---------------- 128^2 bf16 GEMM (m97-structure) for the final projection ----------------
template <int F32OUT>
__global__ __launch_bounds__(256, 2) void k_gemm(const u16* __restrict__ A,
                                                 const u16* __restrict__ Bt,
                                                 void* __restrict__ Cout,
                                                 int M, int Nt, int K) {
  __shared__ u16 As[128 * 32];
  __shared__ u16 Bs[128 * 32];
  const int tid = threadIdx.x, lane = tid & 63, wid = tid >> 6;
  const int m0 = blockIdx.y * 128, n0 = blockIdx.x * 128;
  const int wm = (wid >> 1) * 64, wn = (wid & 1) * 64;
  const int fr = lane & 15, fc = (lane >> 4) * 8;

  f32x4 acc[4][4] = {};

  const u16* gA = A + (size_t)(m0 + wid * 32 + (lane >> 2)) * K + (lane & 3) * 8;
  const u16* gB = Bt + (size_t)(n0 + wid * 32 + (lane >> 2)) * K + (lane & 3) * 8;
  u16* lA = As + wid * 1024;
  u16* lB = Bs + wid * 1024;
  const size_t rowskip = (size_t)16 * K;

  for (int k0 = 0; k0 < K; k0 += 32) {
    gload_lds16(gA + k0, lA);
    gload_lds16(gA + k0 + rowskip, lA + 512);
    gload_lds16(gB + k0, lB);
    gload_lds16(gB + k0 + rowskip, lB + 512);
    __syncthreads();
    u16x8 a[4], b[4];
#pragma unroll
    for (int mi = 0; mi < 4; mi++) a[mi] = *(const u16x8*)(As + (wm + mi * 16 + fr) * 32 + fc);
#pragma unroll
    for (int ni = 0; ni < 4; ni++) b[ni] = *(const u16x8*)(Bs + (wn + ni * 16 + fr) * 32 + fc);
#pragma unroll
    for (int mi = 0; mi < 4; mi++)
#pragma unroll
      for (int ni = 0; ni < 4; ni++)
        acc[mi][ni] = mfma16(a[mi], b[ni], acc[mi][ni]);
    __syncthreads();
  }

  const int frow = (lane >> 4) * 4;
#pragma unroll
  for (int mi = 0; mi < 4; mi++)
#pragma unroll
    for (int ni = 0; ni < 4; ni++)
#pragma unroll
      for (int j = 0; j < 4; j++) {
        const size_t row = m0 + wm + mi * 16 + frow + j;
        const size_t col = n0 + wn + ni * 16 + fr;
        if (F32OUT) ((float*)Cout)[row * Nt + col] = acc[mi][ni][j];
        else ((u16*)Cout)[row * Nt + col] = f2bf(acc[mi][ni][j]);
      }
}

// ---------------- 256^2 8-wave 4-phase counted-vmcnt GEMM (bf16 out) ----------------
// BM=BN=256, BK=64, 512 thr (8 waves, wave owns 2x64 m-rows x 2x32 n-cols interleaved
// across tile halves). LDS [2][256][64] A + same B = 128KB, XOR-swizzled (chunk^=row&7,
// inverse pre-swizzle on global source). Per tile: 4 quadrant phases; stage order
// A0,B0,B1,A1 one tile ahead; counted vmcnt(4) at phases 1-3 (phase 4: audit shows
// no wait/barrier needed). Loads never drain to 0 in the loop.
template <int MH, int NH>
DEVINL void kg_quad(const u16* __restrict__ Ab, const u16* __restrict__ Bb,
                    f32x4 (&acc)[2][4][2][2], int mq64, int nq32,
                    int fr, int hi, int rb7) {
  u16x8 af[4][2], bf[2][2];
#pragma unroll
  for (int mi = 0; mi < 4; mi++)
#pragma unroll
    for (int kk = 0; kk < 2; kk++) {
      const int rrow = MH * 128 + mq64 + mi * 16 + fr;
      af[mi][kk] = *(const u16x8*)(Ab + rrow * 64 + (((kk * 4 + hi) ^ rb7) << 3));
    }
#pragma unroll
  for (int ni = 0; ni < 2; ni++)
#pragma unroll
    for (int kk = 0; kk < 2; kk++) {
      const int rrow = NH * 128 + nq32 + ni * 16 + fr;
      bf[ni][kk] = *(const u16x8*)(Bb + rrow * 64 + (((kk * 4 + hi) ^ rb7) << 3));
    }
  __builtin_amdgcn_s_setprio(1);
#pragma unroll
  for (int kk = 0; kk < 2; kk++)
#pragma unroll
    for (int mi = 0; mi < 4; mi++)
#pragma unroll
      for (int ni = 0; ni < 2; ni++)
        acc[MH][mi][NH][ni] = mfma16(af[mi][kk], bf[ni][kk], acc[MH][mi][NH][ni]);
  __builtin_amdgcn_s_setprio(0);
}

__global__ __launch_bounds__(512, 1) void k_gemm256(const u16* __restrict__ A,
                                                    const u16* __restrict__ Bt,
                                                    u16* __restrict__ C,
                                                    int Nt, int K) {
  extern __shared__ char smem[];
  u16* As = (u16*)smem;             // [2][256][64]
  u16* Bs = (u16*)(smem + 65536);   // [2][256][64]
  const int tid = threadIdx.x, lane = tid & 63, wid = tid >> 6;

  // XCD-aware bijective swizzle (gridDim.x % 8 == 0 by construction)
  const int nbx = Nt >> 8;
  const int cpx = gridDim.x >> 3;
  const int bid = blockIdx.x;
  const int swz = (bid & 7) * cpx + (bid >> 3);
  const int m0 = (swz / nbx) << 8, n0 = (swz % nbx) << 8;

  const int mq64 = (wid >> 2) * 64, nq32 = (wid & 3) * 32;
  const int fr = lane & 15, hi = lane >> 4, frow = hi * 4, rb7 = fr & 7;

  f32x4 acc[2][4][2][2] = {};

  // staging: line l (64 rows) x 8 chunks; lane -> row wid*8+(lane>>3), src chunk
  // pre-swizzled so LDS[r][c] = global[r][c ^ (r&7)] with linear LDS dest.
  const int schunk = ((lane & 7) ^ ((lane >> 3) & 7)) << 3;
  const int srow = wid * 8 + (lane >> 3);
  const u16* ga0 = A + (size_t)(m0 + srow) * K + schunk;
  const u16* gb0 = Bt + (size_t)(n0 + srow) * K + schunk;
  const size_t l64 = (size_t)64 * K;
  const int dwave = wid * 8 * 64;  // u16, wave-uniform

#define SA(P, L, KT) gload_lds16(ga0 + (size_t)(L) * l64 + (KT), As + (P) * 16384 + (L) * 4096 + dwave)
#define SB(P, L, KT) gload_lds16(gb0 + (size_t)(L) * l64 + (KT), Bs + (P) * 16384 + (L) * 4096 + dwave)

  // prologue: tile 0 -> buf 0, order A0(l0,l1), B0(l0,l1), B1(l2,l3), A1(l2,l3)
  SA(0, 0, 0); SA(0, 1, 0);
  SB(0, 0, 0); SB(0, 1, 0);
  SB(0, 2, 0); SB(0, 3, 0);
  SA(0, 2, 0); SA(0, 3, 0);

  const int NTI = K >> 6;
  for (int t = 0; t < NTI; t++) {
    const int p = t & 1, pn = p ^ 1;
    const int ktn = (t < NTI - 1 ? t + 1 : t) << 6;  // clamped (tail stages harmless)
    const u16* Ab = As + p * 16384;
    const u16* Bb = Bs + p * 16384;

    // phase 1: needs A0,B0 of tile t (oldest 4 loads)
    asm volatile("s_waitcnt vmcnt(4)" ::: "memory");
    __builtin_amdgcn_s_barrier();
    asm volatile("" ::: "memory");
    SA(pn, 0, ktn); SA(pn, 1, ktn);
    kg_quad<0, 0>(Ab, Bb, acc, mq64, nq32, fr, hi, rb7);

    // phase 2: needs B1 (oldest 2 of remaining)
    asm volatile("s_waitcnt vmcnt(4)" ::: "memory");
    __builtin_amdgcn_s_barrier();
    asm volatile("" ::: "memory");
    SB(pn, 0, ktn); SB(pn, 1, ktn);
    kg_quad<0, 1>(Ab, Bb, acc, mq64, nq32, fr, hi, rb7);

    // phase 3: needs A1
    asm volatile("s_waitcnt vmcnt(4)" ::: "memory");
    __builtin_amdgcn_s_barrier();
    asm volatile("" ::: "memory");
    SB(pn, 2, ktn); SB(pn, 3, ktn);
    kg_quad<1, 0>(Ab, Bb, acc, mq64, nq32, fr, hi, rb7);

    // phase 4: A1,B1 already waited (p3,p2); stage targets disjoint halves -> no wait/barrier
    SA(pn, 2, ktn); SA(pn, 3, ktn);
    kg_quad<1, 1>(Ab, Bb, acc, mq64, nq32, fr, hi, rb7);
  }
#undef SA
#undef SB

#pragma unroll
  for (int mh = 0; mh < 2; mh++)
#pragma unroll
    for (int mi = 0; mi < 4; mi++)
#pragma unroll
      for (int nh = 0; nh < 2; nh++)
#pragma unroll
        for (int ni = 0; ni < 2; ni++)
#pragma unroll
          for (int j = 0; j < 4; j++) {
            const size_t row = m0 + mh * 128 + mq64 + mi * 16 + frow + j;
            const size_t col = n0 + nh * 128 + nq32 + ni * 16 + fr;
            C[row * Nt + col] = f2bf(acc[mh][mi][nh][ni][j]);
          }
}

// ---------------- normalize: qgkv raw -> qn, kn, vnT, gact ----------------
// vnT stored with sigma-permuted columns within each 32-n group (swap bits 2,3)
// so that attn's PV A-fragment k-order matches the in-register P^T B-fragment.
__global__ __launch_bounds__(256, 4) void k_norm(const u16* __restrict__ qgkv,
                                                 u16* __restrict__ qn, u16* __restrict__ kn,
                                                 u16* __restrict__ vnT, u16* __restrict__ gact) {
  __shared__ u16 vt[128 * 64];  // [d][nl], col swizzle: c' = nl ^ ((d&15)<<2)
  const int tid = threadIdx.x, lane = tid & 63, wid = tid >> 6;
  const int hb = blockIdx.y;            // b*16 + h
  const int h = hb & 15, b = hb >> 4;
  const int n0 = blockIdx.x * 64;

  for (int s = 0; s < 16; s++) {
    const int nl = wid * 16 + s;        // 0..63
    const int n = n0 + nl;
    const size_t bn = (size_t)b * 2048 + n;
    const size_t baseq = bn * 6144 + (size_t)h * 192;
    const size_t basek = baseq + 3072;

    float q = bf2f(qgkv[baseq + lane]);
    float g0 = bf2f(qgkv[baseq + 64 + lane]);
    float g1 = bf2f(qgkv[baseq + 128 + lane]);
    float k = bf2f(qgkv[basek + lane]);
    float v0 = bf2f(qgkv[basek + 64 + lane]);
    float v1 = bf2f(qgkv[basek + 128 + lane]);

    float qs = q * q, ks = k * k, vs = v0 * v0 + v1 * v1;
#pragma unroll
    for (int m = 1; m < 64; m <<= 1) {
      qs += __shfl_xor(qs, m);
      ks += __shfl_xor(ks, m);
      vs += __shfl_xor(vs, m);
    }
    float rq = 1.f / fmaxf(sqrtf(qs), 1e-12f);
    float rk = 1.f / fmaxf(sqrtf(ks), 1e-12f);
    float rv = 1.f / fmaxf(sqrtf(vs), 1e-12f);

    qn[((size_t)hb * 2048 + n) * 64 + lane] = f2bf(q * rq);
    kn[((size_t)hb * 2048 + n) * 64 + lane] = f2bf(k * rk);
    float s0 = g0 / (1.f + __expf(-g0));
    float s1 = g1 / (1.f + __expf(-g1));
    gact[((size_t)hb * 2048 + n) * 128 + lane] = f2bf(tanhf(s0));
    gact[((size_t)hb * 2048 + n) * 128 + 64 + lane] = f2bf(tanhf(s1));

    const int d0 = lane, d1 = 64 + lane;
    vt[d0 * 64 + (nl ^ ((d0 & 15) << 2))] = f2bf(v0 * rv);
    vt[d1 * 64 + (nl ^ ((d1 & 15) << 2))] = f2bf(v1 * rv);
  }
  __syncthreads();

  // write-out: sigma(col) = swap bits 2<->3 within n&31 (preserves bits 0-1)
#pragma unroll
  for (int p = 0; p < 8; p++) {
    const int d = p * 16 + (tid >> 4);
    const int nq = (tid & 15) * 4;
    const int cb = nq ^ ((d & 15) << 2);
    const int nq2 = (nq & ~12) | ((nq & 4) << 1) | ((nq & 8) >> 1);
    ushort4 o;
    o.x = vt[d * 64 + cb + 0];
    o.y = vt[d * 64 + cb + 1];
    o.z = vt[d * 64 + cb + 2];
    o.w = vt[d * 64 + cb + 3];
    *(ushort4*)(vnT + ((size_t)hb * 128 + d) * 2048 + n0 + nq2) = o;
  }
}

// ---------------- fused screened attention (swapped-operand 32x32, P in registers) ----------------
__global__ __launch_bounds__(256, 2) void k_attn(const u16* __restrict__ qn,
                                                 const u16* __restrict__ kn,
                                                 const u16* __restrict__ vnT,
                                                 const u16* __restrict__ gact,
                                                 const float* __restrict__ ls_iaw,
                                                 const float* __restrict__ ls_hws,
                                                 u16* __restrict__ pre_out) {
  extern __shared__ char smem[];
  u16* KsB = (u16*)smem;                 // [2][64 k][64 dk]  8KB each
  u16* VsB = (u16*)(smem + 16384);       // [2][128 d][64 k'] 16KB each (k' sigma-order)
  u16* Os = (u16*)smem;                  // epilogue reuse: [128 q][132 d] 33.8KB

  const int tid = threadIdx.x, lane = tid & 63, wid = tid >> 6;
  const int bid = blockIdx.y * 16 + blockIdx.x;
  const int bh = (bid & 7) * 4 + ((bid >> 3) & 3);
  const int n0 = (bid >> 5) * 128;
  const int h = bh & 15;
  const int l31 = lane & 31, L = lane >> 5, rb = l31 & 7;
  const float r = 1.f / (__expf(ls_iaw[h]) + 1.f);
  const float c1 = 1.f - r;
  const float whs = __expf(ls_hws[h]);

  const int wq = wid * 32;
  const u16* qrow = qn + ((size_t)bh * 2048 + n0 + wq + l31) * 64;
  u16x8 qf[4];
#pragma unroll
  for (int c = 0; c < 4; c++) qf[c] = *(const u16x8*)(qrow + c * 16 + L * 8);

  f32x16 acc[4] = {};  // acc[dt]: D[d = dt*32 + (reg&3)+8*(reg>>2)+4L][q = l31]
  const u16* kbase = kn + (size_t)bh * 2048 * 64;
  const u16* vbase = vnT + (size_t)bh * 128 * 2048;

  int ks_goff[2];
#pragma unroll
  for (int i = 0; i < 2; i++) {
    int row = wid * 16 + i * 8 + (lane >> 3);
    ks_goff[i] = row * 64 + (((lane & 7) ^ (row & 7)) << 3);
  }
  int vs_goff[4];
#pragma unroll
  for (int i = 0; i < 4; i++) {
    int row = wid * 32 + i * 8 + (lane >> 3);
    vs_goff[i] = row * 2048 + (((lane & 7) ^ (row & 7)) << 3);
  }

  {
    u16* KsC = KsB + wid * 1024;
    u16* VsC = VsB + wid * 2048;
#pragma unroll
    for (int i = 0; i < 2; i++) gload_lds16(kbase + ks_goff[i], KsC + i * 512);
#pragma unroll
    for (int i = 0; i < 4; i++) gload_lds16(vbase + vs_goff[i], VsC + i * 512);
  }

  int cur = 0;
  for (int t = 0; t < 32; t++) {
    asm volatile("s_waitcnt vmcnt(0) lgkmcnt(0)" ::: "memory");
    __builtin_amdgcn_s_barrier();
    asm volatile("" ::: "memory");

    if (t < 31) {
      const int kv0 = (t + 1) * 64;
      u16* KsC2 = KsB + (cur ^ 1) * 4096 + wid * 1024;
      u16* VsC2 = VsB + (cur ^ 1) * 8192 + wid * 2048;
#pragma unroll
      for (int i = 0; i < 2; i++) gload_lds16(kbase + (size_t)kv0 * 64 + ks_goff[i], KsC2 + i * 512);
#pragma unroll
      for (int i = 0; i < 4; i++) gload_lds16(vbase + (size_t)vs_goff[i] + kv0, VsC2 + i * 512);
    }

    const u16* KsC = KsB + cur * 4096;
    const u16* VsC = VsB + cur * 8192;

    f32x16 sT0 = {}, sT1 = {};
    __builtin_amdgcn_s_setprio(1);
#pragma unroll
    for (int c = 0; c < 4; c++) {
      u16x8 kf0 = *(const u16x8*)(KsC + (0 + l31) * 64 + (((2 * c + L) ^ rb) << 3));
      u16x8 kf1 = *(const u16x8*)(KsC + (32 + l31) * 64 + (((2 * c + L) ^ rb) << 3));
      sT0 = mfma32(kf0, qf[c], sT0);
      sT1 = mfma32(kf1, qf[c], sT1);
    }
    __builtin_amdgcn_s_setprio(0);

    uint32_t w[2][4][2];
#pragma unroll
    for (int m = 0; m < 4; m++)
#pragma unroll
      for (int p = 0; p < 2; p++) {
        float a0 = fmaxf(0.f, fmaf(r, sT0[4 * m + 2 * p], c1));
        float a1 = fmaxf(0.f, fmaf(r, sT0[4 * m + 2 * p + 1], c1));
        float b0 = fmaxf(0.f, fmaf(r, sT1[4 * m + 2 * p], c1));
        float b1 = fmaxf(0.f, fmaf(r, sT1[4 * m + 2 * p + 1], c1));
        w[0][m][p] = (uint32_t)f2bf(a0 * a0) | ((uint32_t)f2bf(a1 * a1) << 16);
        w[1][m][p] = (uint32_t)f2bf(b0 * b0) | ((uint32_t)f2bf(b1 * b1) << 16);
      }

    __builtin_amdgcn_s_setprio(1);
#pragma unroll
    for (int kt = 0; kt < 2; kt++)
#pragma unroll
      for (int pair = 0; pair < 2; pair++) {
        i32x4 pw;
        pw[0] = (int)w[kt][2 * pair][0];
        pw[1] = (int)w[kt][2 * pair][1];
        pw[2] = (int)w[kt][2 * pair + 1][0];
        pw[3] = (int)w[kt][2 * pair + 1][1];
        u16x8 pf = __builtin_bit_cast(u16x8, pw);
        const int chunk = 4 * kt + 2 * pair + L;
#pragma unroll
        for (int dt = 0; dt < 4; dt++) {
          u16x8 vf = *(const u16x8*)(VsC + (dt * 32 + l31) * 64 + ((chunk ^ rb) << 3));
          acc[dt] = mfma32(vf, pf, acc[dt]);
        }
      }
    __builtin_amdgcn_s_setprio(0);
    cur ^= 1;
  }

  float ss = 0.f;
#pragma unroll
  for (int dt = 0; dt < 4; dt++)
#pragma unroll
    for (int e = 0; e < 16; e++) { float x = acc[dt][e]; ss += x * x; }
  ss += __shfl_xor(ss, 32);
  float nn = sqrtf(ss);
  float scale = tanhf(nn) / fmaxf(nn, 1e-12f) * whs;

  __syncthreads();

  const int q = wq + l31;
  const size_t grow = ((size_t)bh * 2048 + n0 + q) * 128;
#pragma unroll
  for (int dt = 0; dt < 4; dt++)
#pragma unroll
    for (int m = 0; m < 4; m++) {
      const int d = dt * 32 + 8 * m + 4 * L;
      ushort4 gv = *(const ushort4*)(gact + grow + d);
      ushort4 o;
      o.x = f2bf(acc[dt][4 * m + 0] * scale * bf2f(gv.x));
      o.y = f2bf(acc[dt][4 * m + 1] * scale * bf2f(gv.y));
      o.z = f2bf(acc[dt][4 * m + 2] * scale * bf2f(gv.z));
      o.w = f2bf(acc[dt][4 * m + 3] * scale * bf2f(gv.w));
      *(ushort4*)(Os + q * 132 + d) = o;
    }
  __syncthreads();

  const int orow = tid >> 1, oc0 = (tid & 1) * 64;
  const size_t obase = ((size_t)(bh >> 4) * 2048 + n0 + orow) * 2048 + (size_t)h * 128 + oc0;
#pragma unroll
  for (int j = 0; j < 16; j++) {
    ushort4 v = *(const ushort4*)(Os + orow * 132 + oc0 + 4 * j);
    *(ushort4*)(pre_out + obase + 4 * j) = v;
  }
}

extern "C" void kernel_launch(void* const* d_in, const int* in_sizes, int n_in,
                              void* d_out, int out_size, void* d_ws, size_t ws_size,
                              hipStream_t stream) {
  (void)in_sizes; (void)n_in; (void)out_size; (void)ws_size;
  const float* tokens = (const float*)d_in[0];
  const float* Wqg = (const float*)d_in[1];
  const float* Wkv = (const float*)d_in[2];
  const float* Wo = (const float*)d_in[3];
  const float* ls_iaw = (const float*)d_in[4];
  const float* ls_hws = (const float*)d_in[5];
  float* out = (float*)d_out;
  char* ws = (char*)d_ws;

  // workspace layout (phased aliasing, total 109 MB):
  u16* WoT = (u16*)(ws + 0);                     // 8,388,608 B
  char* regA = ws + 8388608;                     // 50,331,648 B
  u16* tok_bf = (u16*)(regA);                    // phase A-B (16.8MB)
  u16* WqgkvT = (u16*)(regA + 16777216);         // phase A-B (25.2MB) [6144][2048]
  u16* qn = (u16*)(regA);                        // phase C-D
  u16* kn = (u16*)(regA + 8388608);
  u16* vnT = (u16*)(regA + 16777216);
  u16* gact = (u16*)(regA + 33554432);
  char* regB = ws + 58720256;                    // 50,331,648 B
  u16* qgkv_raw = (u16*)(regB);                  // phase B-C [4096][6144]
  u16* pre_out = (u16*)(regB);                   // phase D-E

  k_cvt<<<4096, 256, 0, stream>>>(tokens, tok_bf, 8388608);
  k_cvtT<<<dim3(96, 64), 256, 0, stream>>>(Wqg, WqgkvT, 2048, 3072);
  k_cvtT<<<dim3(96, 64), 256, 0, stream>>>(Wkv, WqgkvT + (size_t)3072 * 2048, 2048, 3072);
  k_cvtT<<<dim3(64, 64), 256, 0, stream>>>(Wo, WoT, 2048, 2048);

  // 256^2 8-wave GEMM: grid 384 = (4096/256)*(6144/256), 128KB dynamic LDS
  k_gemm256<<<384, 512, 131072, stream>>>(tok_bf, WqgkvT, qgkv_raw, 6144, 2048);

  k_norm<<<dim3(32, 32), 256, 0, stream>>>(qgkv_raw, qn, kn, vnT, gact);

  k_attn<<<dim3(16, 32), 256, 49152, stream>>>(qn, kn, vnT, gact, ls_iaw, ls_hws, pre_out);

  k_gemm<1><<<dim3(16, 32), 256, 0, stream>>>(pre_out, WoT, out, 4096, 2048, 2048);
}